// Round 1
// baseline (1617.891 us; speedup 1.0000x reference)
//
#include <hip/hip_runtime.h>
#include <stddef.h>

typedef unsigned short u16;
typedef unsigned int u32;

#define B_ 4
#define T_ 2048
#define C_ 1024
#define E_ 8
#define H_ 4096
#define NTOK (B_ * T_)     // 8192
#define NPAIR (NTOK * 2)   // 16384
#define BM 128
#define BN 128
#define BK 64
#define LDK 72             // padded K stride in LDS (elements)
#define MAXTILES 136       // ceil((16384 + 8*127)/128)
#define MAXROWS (MAXTILES * 128)  // 17408

typedef __bf16 bf16x8 __attribute__((ext_vector_type(8)));
typedef float f32x4 __attribute__((ext_vector_type(4)));

__device__ __forceinline__ u16 f2bf(float f) {
    union { float f; u32 u; } c;
    c.f = f;
    u32 r = c.u + 0x7FFFu + ((c.u >> 16) & 1u);  // round-to-nearest-even
    return (u16)(r >> 16);
}

// ---------------- LayerNorm: h = bf16(LN(x)), out = x ----------------
__global__ __launch_bounds__(256) void ln_kernel(
    const float* __restrict__ x, const float* __restrict__ gamma,
    const float* __restrict__ beta, float* __restrict__ out,
    u16* __restrict__ h) {
    const int token = blockIdx.x;
    const int t = threadIdx.x;
    const float* xr = x + (size_t)token * C_;
    float4 v = *(const float4*)(xr + t * 4);
    float s = v.x + v.y + v.z + v.w;
    float ss = v.x * v.x + v.y * v.y + v.z * v.z + v.w * v.w;
    #pragma unroll
    for (int off = 32; off > 0; off >>= 1) {
        s += __shfl_down(s, off);
        ss += __shfl_down(ss, off);
    }
    __shared__ float ws_s[4], ws_q[4];
    const int wave = t >> 6, lane = t & 63;
    if (lane == 0) { ws_s[wave] = s; ws_q[wave] = ss; }
    __syncthreads();
    float S = ws_s[0] + ws_s[1] + ws_s[2] + ws_s[3];
    float Q = ws_q[0] + ws_q[1] + ws_q[2] + ws_q[3];
    float mu = S * (1.0f / C_);
    float var = Q * (1.0f / C_) - mu * mu;
    float rstd = rsqrtf(var + 1e-5f);
    float4 g = *(const float4*)(gamma + t * 4);
    float4 b = *(const float4*)(beta + t * 4);
    ushort4 hv;
    hv.x = f2bf((v.x - mu) * rstd * g.x + b.x);
    hv.y = f2bf((v.y - mu) * rstd * g.y + b.y);
    hv.z = f2bf((v.z - mu) * rstd * g.z + b.z);
    hv.w = f2bf((v.w - mu) * rstd * g.w + b.w);
    *(float4*)(out + (size_t)token * C_ + t * 4) = v;  // out = x (residual base)
    *(ushort4*)(h + (size_t)token * C_ + t * 4) = hv;
}

// ---------------- Expert bucketing ----------------
__global__ void count_kernel(const int* __restrict__ winners, int* __restrict__ counts) {
    int p = blockIdx.x * blockDim.x + threadIdx.x;
    if (p >= NPAIR) return;
    atomicAdd(&counts[winners[p]], 1);
}

__global__ void offsets_kernel(const int* __restrict__ counts, int* __restrict__ padded_off,
                               int* __restrict__ tile_expert) {
    if (threadIdx.x != 0 || blockIdx.x != 0) return;
    int off = 0;
    padded_off[0] = 0;
    for (int e = 0; e < E_; ++e) {
        off += ((counts[e] + 127) >> 7) << 7;
        padded_off[e + 1] = off;
    }
    for (int t = 0; t < MAXTILES; ++t) {
        int r = t * 128;
        int e = -1;
        if (r < off) {
            e = 0;
            while (r >= padded_off[e + 1]) ++e;
        }
        tile_expert[t] = e;
    }
}

__global__ void place_kernel(const int* __restrict__ winners, const float* __restrict__ wts,
                             const int* __restrict__ padded_off, int* __restrict__ pos,
                             int* __restrict__ token_id, float* __restrict__ pair_w) {
    int p = blockIdx.x * blockDim.x + threadIdx.x;
    if (p >= NPAIR) return;
    int e = winners[p];
    int slot = padded_off[e] + atomicAdd(&pos[e], 1);
    token_id[slot] = p >> 1;
    pair_w[slot] = wts[p];
}

// ---------------- Grouped GEMM (both phases) ----------------
// PHASE2=false: hidden[r, :] = bf16(relu(h[tok(r)] @ W1[e])^2)   K=1024, N=4096
// PHASE2=true : out[tok(r), :] += pair_w[r] * (hidden[r] @ W2[e]) K=4096, N=1024
template <bool PHASE2>
__global__ __launch_bounds__(256, 2) void gemm_kernel(
    const u16* __restrict__ Amat, const float* __restrict__ Wmat,
    const int* __restrict__ token_id, const float* __restrict__ pair_w,
    const int* __restrict__ tile_expert, u16* __restrict__ hidden,
    float* __restrict__ out) {
    constexpr int Kdim = PHASE2 ? H_ : C_;
    constexpr int Ndim = PHASE2 ? C_ : H_;
    const int rt = blockIdx.x;
    const int ct = blockIdx.y;
    const int e = tile_expert[rt];
    if (e < 0) return;
    const int tid = threadIdx.x;
    const int n0 = ct * BN;
    const float* Wb = Wmat + (size_t)e * Kdim * Ndim;

    __shared__ u16 As[BM * LDK];
    __shared__ u16 Bs[BN * LDK];

    // A staging: thread pair per row; each thread stages 4x16B contiguous
    const int ar = tid >> 1;
    const int acb = (tid & 1) * 4;
    const u16* asrc;
    bool avalid;
    {
        int grow = rt * BM + ar;
        if (PHASE2) {
            avalid = true;
            asrc = Amat + (size_t)grow * Kdim;
        } else {
            int tok = token_id[grow];
            avalid = tok >= 0;
            asrc = Amat + (size_t)(avalid ? tok : 0) * Kdim;
        }
    }
    // B staging: thread reads 8 k-consecutive fp32 of one column, packs to bf16x8
    const int bn = tid & 127;
    const int bkg = tid >> 7;
    const float* bptr = Wb + n0 + bn;

    const int wave = tid >> 6;
    const int lane = tid & 63;
    const int wr = wave >> 1, wc = wave & 1;
    const int lrow = lane & 15;
    const int quad = lane >> 4;

    f32x4 acc[4][4] = {};

    for (int k0 = 0; k0 < Kdim; k0 += BK) {
        __syncthreads();
        #pragma unroll
        for (int i = 0; i < 4; ++i) {
            int ch = acb + i;
            uint4 v = {0u, 0u, 0u, 0u};
            if (avalid) v = *(const uint4*)(asrc + k0 + ch * 8);
            *(uint4*)&As[ar * LDK + ch * 8] = v;
        }
        #pragma unroll
        for (int i = 0; i < 4; ++i) {
            int k8 = (bkg + 2 * i) * 8;
            alignas(16) u16 tmp[8];
            #pragma unroll
            for (int j = 0; j < 8; ++j)
                tmp[j] = f2bf(bptr[(size_t)(k0 + k8 + j) * Ndim]);
            *(uint4*)&Bs[bn * LDK + k8] = *(uint4*)tmp;
        }
        __syncthreads();
        #pragma unroll
        for (int kk = 0; kk < 2; ++kk) {
            bf16x8 af[4], bfv[4];
            #pragma unroll
            for (int mi = 0; mi < 4; ++mi)
                af[mi] = *(const bf16x8*)&As[(wr * 64 + mi * 16 + lrow) * LDK + kk * 32 + quad * 8];
            #pragma unroll
            for (int ni = 0; ni < 4; ++ni)
                bfv[ni] = *(const bf16x8*)&Bs[(wc * 64 + ni * 16 + lrow) * LDK + kk * 32 + quad * 8];
            #pragma unroll
            for (int mi = 0; mi < 4; ++mi)
                #pragma unroll
                for (int ni = 0; ni < 4; ++ni)
                    acc[mi][ni] = __builtin_amdgcn_mfma_f32_16x16x32_bf16(
                        af[mi], bfv[ni], acc[mi][ni], 0, 0, 0);
        }
    }

    if (!PHASE2) {
        #pragma unroll
        for (int mi = 0; mi < 4; ++mi) {
            int rbase = rt * BM + wr * 64 + mi * 16 + quad * 4;
            #pragma unroll
            for (int ni = 0; ni < 4; ++ni) {
                int col = n0 + wc * 64 + ni * 16 + lrow;
                #pragma unroll
                for (int j = 0; j < 4; ++j) {
                    float v = acc[mi][ni][j];
                    v = fmaxf(v, 0.0f);
                    v = v * v;
                    hidden[(size_t)(rbase + j) * H_ + col] = f2bf(v);
                }
            }
        }
    } else {
        #pragma unroll
        for (int mi = 0; mi < 4; ++mi) {
            int rbase = rt * BM + wr * 64 + mi * 16 + quad * 4;
            #pragma unroll
            for (int j = 0; j < 4; ++j) {
                int grow = rbase + j;
                int tok = token_id[grow];
                if (tok < 0) continue;
                float w = pair_w[grow];
                #pragma unroll
                for (int ni = 0; ni < 4; ++ni) {
                    int col = n0 + wc * 64 + ni * 16 + lrow;
                    atomicAdd(&out[(size_t)tok * C_ + col], w * acc[mi][ni][j]);
                }
            }
        }
    }
}

// ---------------- Launch ----------------
extern "C" void kernel_launch(void* const* d_in, const int* in_sizes, int n_in,
                              void* d_out, int out_size, void* d_ws, size_t ws_size,
                              hipStream_t stream) {
    const float* x = (const float*)d_in[0];
    const float* weights = (const float*)d_in[1];
    const float* gamma = (const float*)d_in[2];
    const float* beta = (const float*)d_in[3];
    const float* W1 = (const float*)d_in[4];
    const float* W2 = (const float*)d_in[5];
    const int* winners = (const int*)d_in[6];
    float* out = (float*)d_out;

    char* ws = (char*)d_ws;
    const size_t OFF_HIDDEN = (size_t)NTOK * C_ * 2;                    // 16 MB
    const size_t OFF_META = OFF_HIDDEN + (size_t)MAXROWS * H_ * 2;      // +136 MB

    u16* h = (u16*)ws;
    u16* hidden = (u16*)(ws + OFF_HIDDEN);
    int* meta = (int*)(ws + OFF_META);
    int* counts = meta;            // 8
    int* pos = meta + 8;           // 8
    int* padded_off = meta + 16;   // 9
    int* tile_expert = meta + 32;  // 136
    int* token_id = meta + 192;    // MAXROWS
    float* pair_w = (float*)(meta + 192 + MAXROWS);

    hipMemsetAsync(meta, 0, 192 * sizeof(int), stream);
    hipMemsetAsync(token_id, 0xFF, (size_t)MAXROWS * sizeof(int), stream);

    ln_kernel<<<NTOK, 256, 0, stream>>>(x, gamma, beta, out, h);
    count_kernel<<<NPAIR / 256, 256, 0, stream>>>(winners, counts);
    offsets_kernel<<<1, 64, 0, stream>>>(counts, padded_off, tile_expert);
    place_kernel<<<NPAIR / 256, 256, 0, stream>>>(winners, weights, padded_off, pos,
                                                  token_id, pair_w);
    gemm_kernel<false><<<dim3(MAXTILES, H_ / BN), 256, 0, stream>>>(
        h, W1, token_id, pair_w, tile_expert, hidden, nullptr);
    gemm_kernel<true><<<dim3(MAXTILES, C_ / BN), 256, 0, stream>>>(
        hidden, W2, token_id, pair_w, tile_expert, nullptr, out);
}

// Round 2
// 961.013 us; speedup vs baseline: 1.6835x; 1.6835x over previous
//
#include <hip/hip_runtime.h>
#include <stddef.h>

typedef unsigned short u16;
typedef unsigned int u32;

#define B_ 4
#define T_ 2048
#define C_ 1024
#define E_ 8
#define H_ 4096
#define NTOK (B_ * T_)     // 8192
#define NPAIR (NTOK * 2)   // 16384
#define BM 128
#define BN 128
#define BK 64              // k-tile (bf16 elements); row = 128 B
#define MAXTILES 136       // ceil((16384 + 8*127)/128)
#define MAXROWS (MAXTILES * 128)  // 17408

typedef __bf16 bf16x8 __attribute__((ext_vector_type(8)));
typedef float f32x4 __attribute__((ext_vector_type(4)));

__device__ __forceinline__ u16 f2bf(float f) {
    union { float f; u32 u; } c;
    c.f = f;
    u32 r = c.u + 0x7FFFu + ((c.u >> 16) & 1u);  // round-to-nearest-even
    return (u16)(r >> 16);
}

// async global->LDS, 16B per lane; LDS dest = wave-uniform base + lane*16
__device__ __forceinline__ void gld16(const void* g, void* l) {
    __builtin_amdgcn_global_load_lds(
        (const __attribute__((address_space(1))) u32*)g,
        (__attribute__((address_space(3))) u32*)l, 16, 0, 0);
}

// ---------------- LayerNorm: h = bf16(LN(x)), out = x ----------------
__global__ __launch_bounds__(256) void ln_kernel(
    const float* __restrict__ x, const float* __restrict__ gamma,
    const float* __restrict__ beta, float* __restrict__ out,
    u16* __restrict__ h) {
    const int token = blockIdx.x;
    const int t = threadIdx.x;
    const float* xr = x + (size_t)token * C_;
    float4 v = *(const float4*)(xr + t * 4);
    float s = v.x + v.y + v.z + v.w;
    float ss = v.x * v.x + v.y * v.y + v.z * v.z + v.w * v.w;
    #pragma unroll
    for (int off = 32; off > 0; off >>= 1) {
        s += __shfl_down(s, off);
        ss += __shfl_down(ss, off);
    }
    __shared__ float ws_s[4], ws_q[4];
    const int wave = t >> 6, lane = t & 63;
    if (lane == 0) { ws_s[wave] = s; ws_q[wave] = ss; }
    __syncthreads();
    float S = ws_s[0] + ws_s[1] + ws_s[2] + ws_s[3];
    float Q = ws_q[0] + ws_q[1] + ws_q[2] + ws_q[3];
    float mu = S * (1.0f / C_);
    float var = Q * (1.0f / C_) - mu * mu;
    float rstd = rsqrtf(var + 1e-5f);
    float4 g = *(const float4*)(gamma + t * 4);
    float4 b = *(const float4*)(beta + t * 4);
    ushort4 hv;
    hv.x = f2bf((v.x - mu) * rstd * g.x + b.x);
    hv.y = f2bf((v.y - mu) * rstd * g.y + b.y);
    hv.z = f2bf((v.z - mu) * rstd * g.z + b.z);
    hv.w = f2bf((v.w - mu) * rstd * g.w + b.w);
    *(float4*)(out + (size_t)token * C_ + t * 4) = v;  // out = x (residual base)
    *(ushort4*)(h + (size_t)token * C_ + t * 4) = hv;
}

// ---------------- Weight convert+transpose: fp32 [E][K][N] -> bf16 [E][N][K] ----
__global__ __launch_bounds__(256) void convert_transpose(
    const float* __restrict__ in, u16* __restrict__ outp, int K, int N) {
    const int e = blockIdx.z;
    const int k0 = blockIdx.y * 32, n0 = blockIdx.x * 32;
    const int tx = threadIdx.x, ty = threadIdx.y;  // 32 x 8
    __shared__ float t[32][33];
    const float* src = in + (size_t)e * K * N;
    u16* dst = outp + (size_t)e * N * K;
    #pragma unroll
    for (int i = 0; i < 4; ++i)
        t[ty + i * 8][tx] = src[(size_t)(k0 + ty + i * 8) * N + n0 + tx];
    __syncthreads();
    #pragma unroll
    for (int i = 0; i < 4; ++i)
        dst[(size_t)(n0 + ty + i * 8) * K + k0 + tx] = f2bf(t[tx][ty + i * 8]);
}

// ---------------- Expert bucketing ----------------
__global__ void count_kernel(const int* __restrict__ winners, int* __restrict__ counts) {
    int p = blockIdx.x * blockDim.x + threadIdx.x;
    if (p >= NPAIR) return;
    atomicAdd(&counts[winners[p]], 1);
}

__global__ void offsets_kernel(const int* __restrict__ counts, int* __restrict__ padded_off,
                               int* __restrict__ tile_expert) {
    if (threadIdx.x != 0 || blockIdx.x != 0) return;
    int off = 0;
    padded_off[0] = 0;
    for (int e = 0; e < E_; ++e) {
        off += ((counts[e] + 127) >> 7) << 7;
        padded_off[e + 1] = off;
    }
    for (int t = 0; t < MAXTILES; ++t) {
        int r = t * 128;
        int e = -1;
        if (r < off) {
            e = 0;
            while (r >= padded_off[e + 1]) ++e;
        }
        tile_expert[t] = e;
    }
}

__global__ void place_kernel(const int* __restrict__ winners, const float* __restrict__ wts,
                             const int* __restrict__ padded_off, int* __restrict__ pos,
                             int* __restrict__ token_id, float* __restrict__ pair_w) {
    int p = blockIdx.x * blockDim.x + threadIdx.x;
    if (p >= NPAIR) return;
    int e = winners[p];
    int slot = padded_off[e] + atomicAdd(&pos[e], 1);
    token_id[slot] = p >> 1;
    pair_w[slot] = wts[p];
}

// ---------------- Grouped GEMM, m97-style async staging + XOR swizzle ---------
// PHASE2=false: hidden[r,:] = bf16(relu(h[tok(r)] @ W1T[e]^T)^2)  K=1024, N=4096
// PHASE2=true : out[tok(r),:] += pair_w[r] * (hidden[r] @ W2T[e]^T) K=4096, N=1024
// B operand (Bmat) is pre-transposed bf16 [E][N][K].
template <bool PHASE2>
__global__ __launch_bounds__(256, 4) void gemm_kernel(
    const u16* __restrict__ Amat, const u16* __restrict__ Bmat,
    const int* __restrict__ token_id, const float* __restrict__ pair_w,
    const int* __restrict__ tile_expert, u16* __restrict__ hidden,
    float* __restrict__ out, const u16* __restrict__ zeropage) {
    constexpr int Kdim = PHASE2 ? H_ : C_;
    constexpr int Ndim = PHASE2 ? C_ : H_;
    const int rt = blockIdx.x;
    const int ct = blockIdx.y;
    const int e = tile_expert[rt];
    if (e < 0) return;
    const int tid = threadIdx.x;
    const int w = tid >> 6;      // wave 0..3
    const int lane = tid & 63;
    const int n0 = ct * BN;
    const u16* Bb = Bmat + (size_t)e * Ndim * Kdim;

    __shared__ u16 As[BM * BK];  // 16 KB, [row][k], row = 128 B
    __shared__ u16 Bs[BN * BK];  // 16 KB, [n][k]

    // Staging geometry: per wave, 4 instrs x (8 rows x 128 B) = 32 rows.
    // Lane i -> row sub = i>>3, k-chunk (16 B) = (i&7) ^ sub  (XOR swizzle;
    // LDS side is fixed lane*16, so we permute the GLOBAL side).
    const int sub = lane >> 3;
    const size_t koffB = (size_t)(((lane & 7) ^ sub) * 16);

    const char* abase[4];
    bool aval[4];
    const char* bbase[4];
    u16* adst[4];
    u16* bdst[4];
    #pragma unroll
    for (int j = 0; j < 4; ++j) {
        const int lrow32 = w * 32 + j * 8 + sub;
        const int grow = rt * BM + lrow32;
        if (PHASE2) {
            aval[j] = true;
            abase[j] = (const char*)(Amat + (size_t)grow * Kdim) + koffB;
        } else {
            int tok = token_id[grow];
            aval[j] = tok >= 0;
            abase[j] = (const char*)(Amat + (size_t)(tok < 0 ? 0 : tok) * Kdim) + koffB;
        }
        bbase[j] = (const char*)(Bb + (size_t)(n0 + lrow32) * Kdim) + koffB;
        adst[j] = &As[(w * 32 + j * 8) * BK];
        bdst[j] = &Bs[(w * 32 + j * 8) * BK];
    }

    const int wr = w >> 1, wc = w & 1;
    const int lrow = lane & 15;
    const int quad = lane >> 4;
    const int rsw = lrow & 7;  // read-side swizzle key

    f32x4 acc[4][4] = {};

    for (int k0 = 0; k0 < Kdim; k0 += BK) {
        __syncthreads();
        const size_t kb = (size_t)k0 * 2;
        #pragma unroll
        for (int j = 0; j < 4; ++j)
            gld16(aval[j] ? abase[j] + kb : (const char*)zeropage, adst[j]);
        #pragma unroll
        for (int j = 0; j < 4; ++j)
            gld16(bbase[j] + kb, bdst[j]);
        __syncthreads();
        #pragma unroll
        for (int kk = 0; kk < 2; ++kk) {
            bf16x8 af[4], bfv[4];
            #pragma unroll
            for (int mi = 0; mi < 4; ++mi) {
                int row = wr * 64 + mi * 16 + lrow;
                int pch = (kk * 4 + quad) ^ rsw;
                af[mi] = *(const bf16x8*)&As[row * BK + pch * 8];
            }
            #pragma unroll
            for (int ni = 0; ni < 4; ++ni) {
                int row = wc * 64 + ni * 16 + lrow;
                int pch = (kk * 4 + quad) ^ rsw;
                bfv[ni] = *(const bf16x8*)&Bs[row * BK + pch * 8];
            }
            #pragma unroll
            for (int mi = 0; mi < 4; ++mi)
                #pragma unroll
                for (int ni = 0; ni < 4; ++ni)
                    acc[mi][ni] = __builtin_amdgcn_mfma_f32_16x16x32_bf16(
                        af[mi], bfv[ni], acc[mi][ni], 0, 0, 0);
        }
    }

    if (!PHASE2) {
        #pragma unroll
        for (int mi = 0; mi < 4; ++mi) {
            int rbase = rt * BM + wr * 64 + mi * 16 + quad * 4;
            #pragma unroll
            for (int ni = 0; ni < 4; ++ni) {
                int col = n0 + wc * 64 + ni * 16 + lrow;
                #pragma unroll
                for (int j = 0; j < 4; ++j) {
                    float v = acc[mi][ni][j];
                    v = fmaxf(v, 0.0f);
                    v = v * v;
                    hidden[(size_t)(rbase + j) * H_ + col] = f2bf(v);
                }
            }
        }
    } else {
        #pragma unroll
        for (int mi = 0; mi < 4; ++mi) {
            int rbase = rt * BM + wr * 64 + mi * 16 + quad * 4;
            #pragma unroll
            for (int j = 0; j < 4; ++j) {
                int grow = rbase + j;
                int tok = token_id[grow];
                if (tok < 0) continue;
                float pw = pair_w[grow];
                #pragma unroll
                for (int ni = 0; ni < 4; ++ni) {
                    int col = n0 + wc * 64 + ni * 16 + lrow;
                    atomicAdd(&out[(size_t)tok * C_ + col], pw * acc[mi][ni][j]);
                }
            }
        }
    }
}

// ---------------- Launch ----------------
extern "C" void kernel_launch(void* const* d_in, const int* in_sizes, int n_in,
                              void* d_out, int out_size, void* d_ws, size_t ws_size,
                              hipStream_t stream) {
    const float* x = (const float*)d_in[0];
    const float* weights = (const float*)d_in[1];
    const float* gamma = (const float*)d_in[2];
    const float* beta = (const float*)d_in[3];
    const float* W1 = (const float*)d_in[4];
    const float* W2 = (const float*)d_in[5];
    const int* winners = (const int*)d_in[6];
    float* out = (float*)d_out;

    char* ws = (char*)d_ws;
    const size_t SZ_H = (size_t)NTOK * C_ * 2;           // 16 MB
    const size_t SZ_HID = (size_t)MAXROWS * H_ * 2;      // 136 MB
    const size_t SZ_WT = (size_t)E_ * H_ * C_ * 2;       // 64 MB each
    const size_t OFF_HID = SZ_H;
    const size_t OFF_W1T = OFF_HID + SZ_HID;
    const size_t OFF_W2T = OFF_W1T + SZ_WT;
    const size_t OFF_META = OFF_W2T + SZ_WT;

    u16* h = (u16*)ws;
    u16* hidden = (u16*)(ws + OFF_HID);
    u16* W1T = (u16*)(ws + OFF_W1T);
    u16* W2T = (u16*)(ws + OFF_W2T);
    int* meta = (int*)(ws + OFF_META);
    int* counts = meta;            // [0,8)
    int* pos = meta + 8;           // [8,16)
    int* padded_off = meta + 16;   // [16,32)
    u16* zeropage = (u16*)(meta + 32);  // [32,48) 64 B, 16B-aligned
    int* tile_expert = meta + 48;  // [48,184)
    int* token_id = meta + 192;
    float* pair_w = (float*)(meta + 192 + MAXROWS);

    hipMemsetAsync(meta, 0, 192 * sizeof(int), stream);
    hipMemsetAsync(token_id, 0xFF, (size_t)MAXROWS * sizeof(int), stream);

    ln_kernel<<<NTOK, 256, 0, stream>>>(x, gamma, beta, out, h);
    convert_transpose<<<dim3(H_ / 32, C_ / 32, E_), dim3(32, 8), 0, stream>>>(W1, W1T, C_, H_);
    convert_transpose<<<dim3(C_ / 32, H_ / 32, E_), dim3(32, 8), 0, stream>>>(W2, W2T, H_, C_);
    count_kernel<<<NPAIR / 256, 256, 0, stream>>>(winners, counts);
    offsets_kernel<<<1, 64, 0, stream>>>(counts, padded_off, tile_expert);
    place_kernel<<<NPAIR / 256, 256, 0, stream>>>(winners, weights, padded_off, pos,
                                                  token_id, pair_w);
    gemm_kernel<false><<<dim3(MAXTILES, H_ / BN), 256, 0, stream>>>(
        h, W1T, token_id, pair_w, tile_expert, hidden, nullptr, zeropage);
    gemm_kernel<true><<<dim3(MAXTILES, C_ / BN), 256, 0, stream>>>(
        hidden, W2T, token_id, pair_w, tile_expert, nullptr, out, zeropage);
}

// Round 3
// 931.933 us; speedup vs baseline: 1.7361x; 1.0312x over previous
//
#include <hip/hip_runtime.h>
#include <stddef.h>

typedef unsigned short u16;
typedef unsigned int u32;

#define B_ 4
#define T_ 2048
#define C_ 1024
#define E_ 8
#define H_ 4096
#define NTOK (B_ * T_)     // 8192
#define NPAIR (NTOK * 2)   // 16384
#define BM 128
#define BN 128
#define BK 64              // k-tile (bf16 elements); row = 128 B
#define MAXTILES 136       // ceil((16384 + 8*127)/128)
#define MAXROWS (MAXTILES * 128)  // 17408

typedef __bf16 bf16x8 __attribute__((ext_vector_type(8)));
typedef float f32x4 __attribute__((ext_vector_type(4)));

__device__ __forceinline__ u16 f2bf(float f) {
    union { float f; u32 u; } c;
    c.f = f;
    u32 r = c.u + 0x7FFFu + ((c.u >> 16) & 1u);  // round-to-nearest-even
    return (u16)(r >> 16);
}

// async global->LDS, 16B per lane; LDS dest = wave-uniform base + lane*16
__device__ __forceinline__ void gld16(const void* g, void* l) {
    __builtin_amdgcn_global_load_lds(
        (const __attribute__((address_space(1))) u32*)g,
        (__attribute__((address_space(3))) u32*)l, 16, 0, 0);
}

// ---------------- LayerNorm: h = bf16(LN(x)), out = x; fused expert count ----
__global__ __launch_bounds__(256) void ln_kernel(
    const float* __restrict__ x, const float* __restrict__ gamma,
    const float* __restrict__ beta, float* __restrict__ out,
    u16* __restrict__ h, const int* __restrict__ winners,
    int* __restrict__ counts) {
    const int token = blockIdx.x;
    const int t = threadIdx.x;
    if (t < 2) atomicAdd(&counts[winners[token * 2 + t]], 1);
    const float* xr = x + (size_t)token * C_;
    float4 v = *(const float4*)(xr + t * 4);
    float s = v.x + v.y + v.z + v.w;
    float ss = v.x * v.x + v.y * v.y + v.z * v.z + v.w * v.w;
    #pragma unroll
    for (int off = 32; off > 0; off >>= 1) {
        s += __shfl_down(s, off);
        ss += __shfl_down(ss, off);
    }
    __shared__ float ws_s[4], ws_q[4];
    const int wave = t >> 6, lane = t & 63;
    if (lane == 0) { ws_s[wave] = s; ws_q[wave] = ss; }
    __syncthreads();
    float S = ws_s[0] + ws_s[1] + ws_s[2] + ws_s[3];
    float Q = ws_q[0] + ws_q[1] + ws_q[2] + ws_q[3];
    float mu = S * (1.0f / C_);
    float var = Q * (1.0f / C_) - mu * mu;
    float rstd = rsqrtf(var + 1e-5f);
    float4 g = *(const float4*)(gamma + t * 4);
    float4 b = *(const float4*)(beta + t * 4);
    ushort4 hv;
    hv.x = f2bf((v.x - mu) * rstd * g.x + b.x);
    hv.y = f2bf((v.y - mu) * rstd * g.y + b.y);
    hv.z = f2bf((v.z - mu) * rstd * g.z + b.z);
    hv.w = f2bf((v.w - mu) * rstd * g.w + b.w);
    *(float4*)(out + (size_t)token * C_ + t * 4) = v;  // out = x (residual base)
    *(ushort4*)(h + (size_t)token * C_ + t * 4) = hv;
}

// ---------------- Weight convert+transpose: fp32 [E][K][N] -> bf16 [E][N][K] --
// PERM: source k-row permuted per 64-block by phi(r)=((r&3)<<4)|(r>>2), matching
// the gemm1 epilogue's packed hidden layout (only used for W2).
template <bool PERM>
__global__ __launch_bounds__(256) void convert_transpose(
    const float* __restrict__ in, u16* __restrict__ outp, int K, int N) {
    const int e = blockIdx.z;
    const int k0 = blockIdx.y * 64, n0 = blockIdx.x * 64;
    const int tx = threadIdx.x & 15, ty = threadIdx.x >> 4;  // 16 x 16
    __shared__ float t[64][69];  // pitch 69: 2-way max bank aliasing on reads
    const float* src = in + (size_t)e * K * N;
    u16* dst = outp + (size_t)e * N * K;
    #pragma unroll
    for (int i = 0; i < 4; ++i) {
        int r = ty + i * 16;  // LDS row (= dst k-offset)
        int kr = PERM ? (((r & 3) << 4) | (r >> 2)) : r;  // src k-offset
        float4 v = *(const float4*)(src + (size_t)(k0 + kr) * N + n0 + tx * 4);
        t[r][tx * 4 + 0] = v.x;
        t[r][tx * 4 + 1] = v.y;
        t[r][tx * 4 + 2] = v.z;
        t[r][tx * 4 + 3] = v.w;
    }
    __syncthreads();
    #pragma unroll
    for (int i = 0; i < 4; ++i) {
        int nl = ty + i * 16;
        ushort4 o;
        o.x = f2bf(t[tx * 4 + 0][nl]);
        o.y = f2bf(t[tx * 4 + 1][nl]);
        o.z = f2bf(t[tx * 4 + 2][nl]);
        o.w = f2bf(t[tx * 4 + 3][nl]);
        *(ushort4*)(dst + (size_t)(n0 + nl) * K + k0 + tx * 4) = o;
    }
}

// ---------------- Expert bucketing ----------------
__global__ void offsets_kernel(const int* __restrict__ counts, int* __restrict__ padded_off,
                               int* __restrict__ tile_expert) {
    if (threadIdx.x != 0 || blockIdx.x != 0) return;
    int off = 0;
    padded_off[0] = 0;
    for (int e = 0; e < E_; ++e) {
        off += ((counts[e] + 127) >> 7) << 7;
        padded_off[e + 1] = off;
    }
    for (int t = 0; t < MAXTILES; ++t) {
        int r = t * 128;
        int e = -1;
        if (r < off) {
            e = 0;
            while (r >= padded_off[e + 1]) ++e;
        }
        tile_expert[t] = e;
    }
}

__global__ void place_kernel(const int* __restrict__ winners, const float* __restrict__ wts,
                             const int* __restrict__ padded_off, int* __restrict__ pos,
                             int* __restrict__ token_id, float* __restrict__ pair_w) {
    int p = blockIdx.x * blockDim.x + threadIdx.x;
    if (p >= NPAIR) return;
    int e = winners[p];
    int slot = padded_off[e] + atomicAdd(&pos[e], 1);
    token_id[slot] = p >> 1;
    pair_w[slot] = wts[p];
}

// ---------------- Grouped GEMM, m97-style async staging + XOR swizzle ---------
// PHASE2=false: hidden[r,:] = bf16(relu(h[tok(r)] @ W1T[e]^T)^2)  K=1024, N=4096
//               hidden K-dim stored permuted: p64 = lrow*4 + ni
// PHASE2=true : out[tok(r),:] += pair_w[r] * (hidden[r] @ W2T[e]^T) K=4096, N=1024
// B operand (Bmat) is pre-transposed bf16 [E][N][K] (W2T rows phi-permuted).
// Grid: x = column tile (fast: concurrent blocks share the A-slab), y = row tile.
template <bool PHASE2>
__global__ __launch_bounds__(256, 4) void gemm_kernel(
    const u16* __restrict__ Amat, const u16* __restrict__ Bmat,
    const int* __restrict__ token_id, const float* __restrict__ pair_w,
    const int* __restrict__ tile_expert, u16* __restrict__ hidden,
    float* __restrict__ out, const u16* __restrict__ zeropage) {
    constexpr int Kdim = PHASE2 ? H_ : C_;
    constexpr int Ndim = PHASE2 ? C_ : H_;
    const int ct = blockIdx.x;
    const int rt = blockIdx.y;
    const int e = tile_expert[rt];
    if (e < 0) return;
    const int tid = threadIdx.x;
    const int w = tid >> 6;      // wave 0..3
    const int lane = tid & 63;
    const int n0 = ct * BN;
    const u16* Bb = Bmat + (size_t)e * Ndim * Kdim;

    __shared__ u16 As[BM * BK];  // 16 KB, [row][k], row = 128 B
    __shared__ u16 Bs[BN * BK];  // 16 KB, [n][k]

    // Staging geometry: per wave, 4 instrs x (8 rows x 128 B) = 32 rows.
    // Lane i -> row sub = i>>3, k-chunk (16 B) = (i&7) ^ sub  (XOR swizzle;
    // LDS side is fixed lane*16, so we permute the GLOBAL side).
    const int sub = lane >> 3;
    const size_t koffB = (size_t)(((lane & 7) ^ sub) * 16);

    const char* abase[4];
    bool aval[4];
    const char* bbase[4];
    u16* adst[4];
    u16* bdst[4];
    #pragma unroll
    for (int j = 0; j < 4; ++j) {
        const int lrow32 = w * 32 + j * 8 + sub;
        const int grow = rt * BM + lrow32;
        if (PHASE2) {
            aval[j] = true;
            abase[j] = (const char*)(Amat + (size_t)grow * Kdim) + koffB;
        } else {
            int tok = token_id[grow];
            aval[j] = tok >= 0;
            abase[j] = (const char*)(Amat + (size_t)(tok < 0 ? 0 : tok) * Kdim) + koffB;
        }
        bbase[j] = (const char*)(Bb + (size_t)(n0 + lrow32) * Kdim) + koffB;
        adst[j] = &As[(w * 32 + j * 8) * BK];
        bdst[j] = &Bs[(w * 32 + j * 8) * BK];
    }

    const int wr = w >> 1, wc = w & 1;
    const int lrow = lane & 15;
    const int quad = lane >> 4;
    const int rsw = lrow & 7;  // read-side swizzle key

    f32x4 acc[4][4] = {};

    for (int k0 = 0; k0 < Kdim; k0 += BK) {
        __syncthreads();
        const size_t kb = (size_t)k0 * 2;
        #pragma unroll
        for (int j = 0; j < 4; ++j)
            gld16(aval[j] ? abase[j] + kb : (const char*)zeropage, adst[j]);
        #pragma unroll
        for (int j = 0; j < 4; ++j)
            gld16(bbase[j] + kb, bdst[j]);
        __syncthreads();
        #pragma unroll
        for (int kk = 0; kk < 2; ++kk) {
            bf16x8 af[4], bfv[4];
            #pragma unroll
            for (int mi = 0; mi < 4; ++mi) {
                int row = wr * 64 + mi * 16 + lrow;
                int pch = (kk * 4 + quad) ^ rsw;
                af[mi] = *(const bf16x8*)&As[row * BK + pch * 8];
            }
            #pragma unroll
            for (int ni = 0; ni < 4; ++ni) {
                int row = wc * 64 + ni * 16 + lrow;
                int pch = (kk * 4 + quad) ^ rsw;
                bfv[ni] = *(const bf16x8*)&Bs[row * BK + pch * 8];
            }
            #pragma unroll
            for (int mi = 0; mi < 4; ++mi)
                #pragma unroll
                for (int ni = 0; ni < 4; ++ni)
                    acc[mi][ni] = __builtin_amdgcn_mfma_f32_16x16x32_bf16(
                        af[mi], bfv[ni], acc[mi][ni], 0, 0, 0);
        }
    }

    if (!PHASE2) {
        // Packed store: per (mi,j)-row, lane's 4 ni-values go to permuted
        // k' = n0 + wc*64 + lrow*4 + ni  -> one ushort4 (8 B) store.
        #pragma unroll
        for (int mi = 0; mi < 4; ++mi) {
            int rbase = rt * BM + wr * 64 + mi * 16 + quad * 4;
            #pragma unroll
            for (int j = 0; j < 4; ++j) {
                ushort4 o;
                float v0 = fmaxf(acc[mi][0][j], 0.0f);
                float v1 = fmaxf(acc[mi][1][j], 0.0f);
                float v2 = fmaxf(acc[mi][2][j], 0.0f);
                float v3 = fmaxf(acc[mi][3][j], 0.0f);
                o.x = f2bf(v0 * v0);
                o.y = f2bf(v1 * v1);
                o.z = f2bf(v2 * v2);
                o.w = f2bf(v3 * v3);
                *(ushort4*)&hidden[(size_t)(rbase + j) * H_ + n0 + wc * 64 + lrow * 4] = o;
            }
        }
    } else {
        #pragma unroll
        for (int mi = 0; mi < 4; ++mi) {
            int rbase = rt * BM + wr * 64 + mi * 16 + quad * 4;
            #pragma unroll
            for (int j = 0; j < 4; ++j) {
                int grow = rbase + j;
                int tok = token_id[grow];
                if (tok < 0) continue;
                float pw = pair_w[grow];
                #pragma unroll
                for (int ni = 0; ni < 4; ++ni) {
                    int col = n0 + wc * 64 + ni * 16 + lrow;
                    atomicAdd(&out[(size_t)tok * C_ + col], pw * acc[mi][ni][j]);
                }
            }
        }
    }
}

// ---------------- Launch ----------------
extern "C" void kernel_launch(void* const* d_in, const int* in_sizes, int n_in,
                              void* d_out, int out_size, void* d_ws, size_t ws_size,
                              hipStream_t stream) {
    const float* x = (const float*)d_in[0];
    const float* weights = (const float*)d_in[1];
    const float* gamma = (const float*)d_in[2];
    const float* beta = (const float*)d_in[3];
    const float* W1 = (const float*)d_in[4];
    const float* W2 = (const float*)d_in[5];
    const int* winners = (const int*)d_in[6];
    float* out = (float*)d_out;

    char* ws = (char*)d_ws;
    const size_t SZ_H = (size_t)NTOK * C_ * 2;           // 16 MB
    const size_t SZ_HID = (size_t)MAXROWS * H_ * 2;      // 136 MB
    const size_t SZ_WT = (size_t)E_ * H_ * C_ * 2;       // 64 MB each
    const size_t OFF_HID = SZ_H;
    const size_t OFF_W1T = OFF_HID + SZ_HID;
    const size_t OFF_W2T = OFF_W1T + SZ_WT;
    const size_t OFF_META = OFF_W2T + SZ_WT;

    u16* h = (u16*)ws;
    u16* hidden = (u16*)(ws + OFF_HID);
    u16* W1T = (u16*)(ws + OFF_W1T);
    u16* W2T = (u16*)(ws + OFF_W2T);
    int* meta = (int*)(ws + OFF_META);
    int* counts = meta;            // [0,8)
    int* pos = meta + 8;           // [8,16)
    int* padded_off = meta + 16;   // [16,32)
    u16* zeropage = (u16*)(meta + 32);  // [32,48) 64 B, 16B-aligned
    int* tile_expert = meta + 48;  // [48,184)
    int* token_id = meta + 192;
    float* pair_w = (float*)(meta + 192 + MAXROWS);

    hipMemsetAsync(meta, 0, 192 * sizeof(int), stream);
    hipMemsetAsync(token_id, 0xFF, (size_t)MAXROWS * sizeof(int), stream);

    ln_kernel<<<NTOK, 256, 0, stream>>>(x, gamma, beta, out, h, winners, counts);
    convert_transpose<false><<<dim3(H_ / 64, C_ / 64, E_), 256, 0, stream>>>(W1, W1T, C_, H_);
    convert_transpose<true><<<dim3(C_ / 64, H_ / 64, E_), 256, 0, stream>>>(W2, W2T, H_, C_);
    offsets_kernel<<<1, 64, 0, stream>>>(counts, padded_off, tile_expert);
    place_kernel<<<NPAIR / 256, 256, 0, stream>>>(winners, weights, padded_off, pos,
                                                  token_id, pair_w);
    gemm_kernel<false><<<dim3(H_ / BN, MAXTILES), 256, 0, stream>>>(
        h, W1T, token_id, pair_w, tile_expert, hidden, nullptr, zeropage);
    gemm_kernel<true><<<dim3(C_ / BN, MAXTILES), 256, 0, stream>>>(
        hidden, W2T, token_id, pair_w, tile_expert, nullptr, out, zeropage);
}